// Round 4
// baseline (306.925 us; speedup 1.0000x reference)
//
#include <hip/hip_runtime.h>

#define B_    16
#define L_    2048
#define D1_   512
#define G_    2
#define V_    320
#define GV_   640
#define DG_   384
#define OUT0_ ((size_t)B_ * L_ * G_ * DG_)
#define WS_BYTES_ ((size_t)GV_ * D1_ * 2u)   // 655360: bf16-hi plane of W in frag layout
#define THR_ 4e-3f

typedef __attribute__((ext_vector_type(8))) short          s16x8;
typedef __attribute__((ext_vector_type(8))) unsigned short u16x8;
typedef __attribute__((ext_vector_type(4))) float          f32x4;
typedef __attribute__((ext_vector_type(4))) int            s32x4;

__device__ __forceinline__ unsigned short f2bf(float x) {
    unsigned u = __float_as_uint(x);
    u += 0x7fffu + ((u >> 16) & 1u);
    return (unsigned short)(u >> 16);
}
__device__ __forceinline__ float bf2f(unsigned short h) {
    return __uint_as_float(((unsigned)h) << 16);
}
__device__ __forceinline__ void merge2(float& m1, int& i1, float& m2, int& i2,
                                       float om1, int oi1, float om2, int oi2) {
    if (om1 > m1 || (om1 == m1 && oi1 < i1)) {
        if (m1 > om2 || (m1 == om2 && i1 < oi2)) { m2 = m1; i2 = i1; }
        else                                     { m2 = om2; i2 = oi2; }
        m1 = om1; i1 = oi1;
    } else if (om1 > m2 || (om1 == m2 && oi1 < i2)) { m2 = om1; i2 = oi1; }
}
__device__ __forceinline__ void cvt8(const float4& v0, const float4& v1, u16x8& hi, u16x8& lo) {
    float a[8] = {v0.x, v0.y, v0.z, v0.w, v1.x, v1.y, v1.z, v1.w};
#pragma unroll
    for (int i = 0; i < 8; ++i) {
        unsigned short h = f2bf(a[i]);
        hi[i] = h;
        lo[i] = f2bf(a[i] - bf2f(h));
    }
}

// W (640x512 fp32) -> ws: bf16 HI plane, MFMA B-frag layout.
// element (o,k): ch=o>>4, kk=k>>5, slot=(o&15)+16*((k>>3)&3), j=k&7
__global__ void prep_w_kernel(const float* __restrict__ W, unsigned short* __restrict__ ws) {
    int flat = blockIdx.x * 256 + threadIdx.x;   // 81920 threads, float4 each
    int o  = flat >> 7;
    int j0 = (flat & 127) << 2;
    float4 v = *(const float4*)(W + (size_t)o * D1_ + j0);
    float vv[4] = {v.x, v.y, v.z, v.w};
    int ch = o >> 4, kk = j0 >> 5;
    int slot = (o & 15) + (((j0 >> 3) & 3) << 4);
    size_t off = (((size_t)(ch * 16 + kk) * 64 + slot) << 3) + (j0 & 7);
    ws[off + 0] = f2bf(vv[0]); ws[off + 1] = f2bf(vv[1]);
    ws[off + 2] = f2bf(vv[2]); ws[off + 3] = f2bf(vv[3]);
}

// 1024 blocks = 512 l-quads x 2 groups. Block: 64 rows (16 b x 4 l, row = li*16 + b),
// 320 cols (one g). 8 waves = 4 rg (16 rows) x 2 cg (160 cols); wave acc = 10 f32x4.
template<bool HAS_WS>
__global__ __launch_bounds__(512, 8) void gvq4_kernel(
    const float* __restrict__ hidden,
    const float* __restrict__ W,
    const float* __restrict__ bias,
    const float* __restrict__ cb,
    const float* __restrict__ gn,
    float* __restrict__ out,
    const unsigned short* __restrict__ ws)
{
    __shared__ unsigned short Abuf[2][2][2048];          // [dbuf][hi/lo][4 chunks x 1 KB]
    __shared__ unsigned short Wb[HAS_WS ? 64 : 10240];   // fallback W-hi frag staging
    __shared__ float pm1[2][64], pm2[2][64], plx[2][64], psum[2][64];
    __shared__ int   pi1[2][64], pi2[2][64], IDX[64];

    const int tid  = threadIdx.x;
    const int w    = tid >> 6, lane = tid & 63;
    const int rg   = w >> 1, cg = w & 1;
    const int q    = lane >> 4, c = lane & 15;

    // XCD pairing: blocks d and d+8 (g=0/1 of same l-quad) -> same XCD
    const int d  = blockIdx.x;
    const int g  = (d >> 3) & 1;
    const int lq = (d >> 4) * 8 + (d & 7);
    const size_t lbase = (size_t)lq * 4;

    // ---- A staging map: 256 tasks x 2 planes; task -> (row r_, k-quarter kq) ----
    const int task = tid & 255, plane = tid >> 8;
    const int r_ = task >> 2, kq = task & 3;
    const int ab = r_ & 15, ali = r_ >> 4;               // b, l-in-quad
    const float* aptr = hidden + ((size_t)ab * L_ + (lbase + ali)) * D1_ + kq * 8;
    const int awoff = ali * 1024 + (((ab + kq * 16) << 4) ^ (kq << 4));
    const int rdoff = (lane << 4) ^ (lane & 48);         // swizzled frag-read byte offset

    f32x4 acc[10];
#pragma unroll
    for (int cf = 0; cf < 10; ++cf) acc[cf] = (f32x4){0.f, 0.f, 0.f, 0.f};

    const unsigned short* wsb = ws + ((size_t)(g * 20 + cg * 10) << 13) + (lane << 3);

    // ---- prologue: stage A(0) (+W(0) fallback) ----
    {
        float4 v0 = *(const float4*)(aptr);
        float4 v1 = *(const float4*)(aptr + 4);
        u16x8 hv, lv; cvt8(v0, v1, hv, lv);
        if (plane == 0) *(u16x8*)((char*)Abuf[0][0] + awoff) = hv;
        else            *(u16x8*)((char*)Abuf[0][1] + awoff) = lv;
        if (!HAS_WS) {
#pragma unroll
            for (int i = 0; i < 3; ++i) {
                int ti = tid + i * 512;
                if (ti < 1280) {
                    int oc = ti >> 2, kq2 = ti & 3;
                    const float* wp = W + ((size_t)(g * V_ + oc)) * D1_ + kq2 * 8;
                    float4 w0 = *(const float4*)(wp), w1 = *(const float4*)(wp + 4);
                    u16x8 h, l; cvt8(w0, w1, h, l);
                    int off = (oc >> 4) * 1024 + (((((oc & 15) + kq2 * 16) << 4)) ^ (kq2 << 4));
                    *(u16x8*)((char*)Wb + off) = h;
                }
            }
        }
    }

    int cur = 0;
#pragma unroll 1
    for (int kk = 0; kk < 16; ++kk) {
        float4 av0, av1, w00[3], w01[3];
        if (kk < 15) {
            av0 = *(const float4*)(aptr + (kk + 1) * 32);
            av1 = *(const float4*)(aptr + (kk + 1) * 32 + 4);
            if (!HAS_WS) {
#pragma unroll
                for (int i = 0; i < 3; ++i) {
                    int ti = tid + i * 512;
                    if (ti < 1280) {
                        int oc = ti >> 2, kq2 = ti & 3;
                        const float* wp = W + ((size_t)(g * V_ + oc)) * D1_ + (kk + 1) * 32 + kq2 * 8;
                        w00[i] = *(const float4*)(wp); w01[i] = *(const float4*)(wp + 4);
                    }
                }
            }
        }
        __syncthreads();

        const char* abh = (const char*)Abuf[cur][0] + rg * 1024 + rdoff;
        const char* abl = (const char*)Abuf[cur][1] + rg * 1024 + rdoff;
        s16x8 ah = *(const s16x8*)abh;
        s16x8 al = *(const s16x8*)abl;
#pragma unroll
        for (int cf = 0; cf < 10; ++cf) {
            s16x8 bh;
            if (HAS_WS) bh = *(const s16x8*)(wsb + cf * 8192 + kk * 512);
            else        bh = *(const s16x8*)((const char*)Wb + (cg * 10 + cf) * 1024 + rdoff);
            acc[cf] = __builtin_amdgcn_mfma_f32_16x16x32_bf16(ah, bh, acc[cf], 0, 0, 0);
            acc[cf] = __builtin_amdgcn_mfma_f32_16x16x32_bf16(al, bh, acc[cf], 0, 0, 0);
        }
        if (!HAS_WS) __syncthreads();
        if (kk < 15) {
            u16x8 hv, lv; cvt8(av0, av1, hv, lv);
            if (plane == 0) *(u16x8*)((char*)Abuf[cur ^ 1][0] + awoff) = hv;
            else            *(u16x8*)((char*)Abuf[cur ^ 1][1] + awoff) = lv;
            if (!HAS_WS) {
#pragma unroll
                for (int i = 0; i < 3; ++i) {
                    int ti = tid + i * 512;
                    if (ti < 1280) {
                        int oc = ti >> 2, kq2 = ti & 3;
                        u16x8 h, l; cvt8(w00[i], w01[i], h, l);
                        int off = (oc >> 4) * 1024 + (((((oc & 15) + kq2 * 16) << 4)) ^ (kq2 << 4));
                        *(u16x8*)((char*)Wb + off) = h;
                    }
                }
            }
            cur ^= 1;
        }
    }

    // ---- E1: bias ----
    const int lcol0 = cg * 160 + c;
    float bv[10];
#pragma unroll
    for (int cf = 0; cf < 10; ++cf) bv[cf] = bias[g * V_ + lcol0 + cf * 16];
#pragma unroll
    for (int cf = 0; cf < 10; ++cf)
#pragma unroll
        for (int r = 0; r < 4; ++r) acc[cf][r] += bv[cf];

    // ---- E2: per-row top2(logit+gumbel) + max(logit), per cg ----
    {
        const size_t lg2 = lbase + rg;
        size_t gbase[4];
#pragma unroll
        for (int r = 0; r < 4; ++r)
            gbase[r] = (((size_t)(q * 4 + r) * L_ + lg2) * G_ + g) * V_ + lcol0;
        float m1[4], m2[4], lx[4]; int i1[4], i2[4];
#pragma unroll
        for (int r = 0; r < 4; ++r) { m1[r] = -3e38f; m2[r] = -3e38f; lx[r] = -3e38f; i1[r] = 0; i2[r] = 0; }
#pragma unroll
        for (int cf = 0; cf < 10; ++cf) {
            const int col = lcol0 + cf * 16;
#pragma unroll
            for (int r = 0; r < 4; ++r) {
                float lg = acc[cf][r];
                float s  = lg + gn[gbase[r] + cf * 16];
                lx[r] = fmaxf(lx[r], lg);
                if (s > m1[r])      { m2[r] = m1[r]; i2[r] = i1[r]; m1[r] = s; i1[r] = col; }
                else if (s > m2[r]) { m2[r] = s; i2[r] = col; }
            }
        }
#pragma unroll
        for (int mk = 1; mk <= 8; mk <<= 1) {
#pragma unroll
            for (int r = 0; r < 4; ++r) {
                float om1 = __shfl_xor(m1[r], mk); int oi1 = __shfl_xor(i1[r], mk);
                float om2 = __shfl_xor(m2[r], mk); int oi2 = __shfl_xor(i2[r], mk);
                lx[r] = fmaxf(lx[r], __shfl_xor(lx[r], mk));
                merge2(m1[r], i1[r], m2[r], i2[r], om1, oi1, om2, oi2);
            }
        }
        if (c == 0) {
            int row0 = rg * 16 + q * 4;
            *(f32x4*)&pm1[cg][row0] = (f32x4){m1[0], m1[1], m1[2], m1[3]};
            *(s32x4*)&pi1[cg][row0] = (s32x4){i1[0], i1[1], i1[2], i1[3]};
            *(f32x4*)&pm2[cg][row0] = (f32x4){m2[0], m2[1], m2[2], m2[3]};
            *(s32x4*)&pi2[cg][row0] = (s32x4){i2[0], i2[1], i2[2], i2[3]};
            *(f32x4*)&plx[cg][row0] = (f32x4){lx[0], lx[1], lx[2], lx[3]};
        }
    }
    __syncthreads();

    // ---- E3a: row max -> exp -> row sum ----
    {
        int row0 = rg * 16 + q * 4;
        float LM[4], se[4];
#pragma unroll
        for (int r = 0; r < 4; ++r) { LM[r] = fmaxf(plx[0][row0 + r], plx[1][row0 + r]); se[r] = 0.f; }
#pragma unroll
        for (int cf = 0; cf < 10; ++cf)
#pragma unroll
            for (int r = 0; r < 4; ++r) {
                float e = __expf(acc[cf][r] - LM[r]);
                acc[cf][r] = e; se[r] += e;
            }
#pragma unroll
        for (int mk = 1; mk <= 8; mk <<= 1)
#pragma unroll
            for (int r = 0; r < 4; ++r) se[r] += __shfl_xor(se[r], mk);
        if (c == 0) *(f32x4*)&psum[cg][row0] = (f32x4){se[0], se[1], se[2], se[3]};
    }
    __syncthreads();

    // ---- E3b: scale, b-sum (r + q-shuffles), direct nt perp store ----
    {
        int row0 = rg * 16 + q * 4;
        float IZ[4];
#pragma unroll
        for (int r = 0; r < 4; ++r) IZ[r] = 1.0f / ((psum[0][row0 + r] + psum[1][row0 + r]) * 16.0f);
        size_t obase = OUT0_ + (lbase + rg) * GV_ + g * V_ + lcol0;
#pragma unroll
        for (int cf = 0; cf < 10; ++cf) {
            float pp = acc[cf][0] * IZ[0] + acc[cf][1] * IZ[1]
                     + acc[cf][2] * IZ[2] + acc[cf][3] * IZ[3];
            pp += __shfl_xor(pp, 16); pp += __shfl_xor(pp, 32);
            if (q == 0) __builtin_nontemporal_store(pp, &out[obase + cf * 16]);
        }
    }

    // ---- E6: argmax finalize + rare fp64 refine ----
    if (tid < 64) {
        const int row = tid;
        float M1 = pm1[0][row]; int I1 = pi1[0][row];
        float M2 = pm2[0][row]; int I2 = pi2[0][row];
        merge2(M1, I1, M2, I2, pm1[1][row], pi1[1][row], pm2[1][row], pi2[1][row]);
        int idx = I1;
        if (M1 - M2 < THR_) {
            const int b = row & 15, li = row >> 4;
            const size_t lg2 = lbase + li;
            const float* ar = hidden + ((size_t)b * L_ + lg2) * D1_;
            const int o1 = g * V_ + I1, o2 = g * V_ + I2;
            double s1 = (double)bias[o1], s2 = (double)bias[o2];
            const float* w1 = W + (size_t)o1 * D1_;
            const float* w2 = W + (size_t)o2 * D1_;
#pragma unroll 4
            for (int k = 0; k < D1_; ++k) {
                double a = (double)ar[k];
                s1 = fma(a, (double)w1[k], s1);
                s2 = fma(a, (double)w2[k], s2);
            }
            const size_t gb = (((size_t)b * L_ + lg2) * G_ + g) * V_;
            s1 += (double)gn[gb + I1]; s2 += (double)gn[gb + I2];
            if (s2 > s1 || (s2 == s1 && I2 < I1)) idx = I2;
        }
        IDX[row] = idx;
    }
    __syncthreads();

    // ---- E7: code-vector gather, nt stores ----
#pragma unroll 1
    for (int it = 0; it < 12; ++it) {
        int i = tid + it * 512;                 // 0..6143 float4-tasks (64 rows x 96)
        int row = i / 96, f = i - row * 96;
        int v = IDX[row];
        int b = row & 15, li = row >> 4;
        f32x4 val = *(const f32x4*)(cb + ((size_t)(g * V_ + v) * DG_) + f * 4);
        __builtin_nontemporal_store(val,
            (f32x4*)(out + ((size_t)b * L_ + lbase + li) * (G_ * DG_) + g * DG_ + f * 4));
    }
}

extern "C" void kernel_launch(void* const* d_in, const int* in_sizes, int n_in,
                              void* d_out, int out_size, void* d_ws, size_t ws_size,
                              hipStream_t stream) {
    const float* hidden   = (const float*)d_in[0];
    const float* W        = (const float*)d_in[1];
    const float* bias     = (const float*)d_in[2];
    const float* codebook = (const float*)d_in[3];
    const float* gumbel   = (const float*)d_in[4];
    float* out = (float*)d_out;

    if (ws_size >= WS_BYTES_) {
        prep_w_kernel<<<320, 256, 0, stream>>>(W, (unsigned short*)d_ws);
        gvq4_kernel<true><<<1024, 512, 0, stream>>>(hidden, W, bias, codebook, gumbel, out,
                                                    (const unsigned short*)d_ws);
    } else {
        gvq4_kernel<false><<<1024, 512, 0, stream>>>(hidden, W, bias, codebook, gumbel, out,
                                                     (const unsigned short*)d_ws);
    }
}

// Round 5
// 192.672 us; speedup vs baseline: 1.5930x; 1.5930x over previous
//
#include <hip/hip_runtime.h>

#define B_    16
#define L_    2048
#define D1_   512
#define G_    2
#define V_    320
#define GV_   640
#define DG_   384
#define OUT0_ ((size_t)B_ * L_ * G_ * DG_)
#define WS_BYTES_ ((size_t)GV_ * D1_ * 2u)   // 655360: bf16-hi plane of W in frag layout
#define THR_ 4e-3f

typedef __attribute__((ext_vector_type(8))) short          s16x8;
typedef __attribute__((ext_vector_type(8))) unsigned short u16x8;
typedef __attribute__((ext_vector_type(4))) float          f32x4;
typedef __attribute__((ext_vector_type(4))) int            s32x4;

__device__ __forceinline__ unsigned short f2bf(float x) {
    unsigned u = __float_as_uint(x);
    u += 0x7fffu + ((u >> 16) & 1u);
    return (unsigned short)(u >> 16);
}
__device__ __forceinline__ float bf2f(unsigned short h) {
    return __uint_as_float(((unsigned)h) << 16);
}
__device__ __forceinline__ void merge2(float& m1, int& i1, float& m2, int& i2,
                                       float om1, int oi1, float om2, int oi2) {
    if (om1 > m1 || (om1 == m1 && oi1 < i1)) {
        if (m1 > om2 || (m1 == om2 && i1 < oi2)) { m2 = m1; i2 = i1; }
        else                                     { m2 = om2; i2 = oi2; }
        m1 = om1; i1 = oi1;
    } else if (om1 > m2 || (om1 == m2 && oi1 < i2)) { m2 = om1; i2 = oi1; }
}
__device__ __forceinline__ void cvt8(const float4& v0, const float4& v1, u16x8& hi, u16x8& lo) {
    float a[8] = {v0.x, v0.y, v0.z, v0.w, v1.x, v1.y, v1.z, v1.w};
#pragma unroll
    for (int i = 0; i < 8; ++i) {
        unsigned short h = f2bf(a[i]);
        hi[i] = h;
        lo[i] = f2bf(a[i] - bf2f(h));
    }
}

// W (640x512 fp32) -> ws: bf16 HI plane, MFMA B-frag layout.
// element (o,k): ch=o>>4, kk=k>>5, slot=(o&15)+16*((k>>3)&3), j=k&7
__global__ void prep_w_kernel(const float* __restrict__ W, unsigned short* __restrict__ ws) {
    int flat = blockIdx.x * 256 + threadIdx.x;   // 81920 threads, float4 each
    int o  = flat >> 7;
    int j0 = (flat & 127) << 2;
    float4 v = *(const float4*)(W + (size_t)o * D1_ + j0);
    float vv[4] = {v.x, v.y, v.z, v.w};
    int ch = o >> 4, kk = j0 >> 5;
    int slot = (o & 15) + (((j0 >> 3) & 3) << 4);
    size_t off = (((size_t)(ch * 16 + kk) * 64 + slot) << 3) + (j0 & 7);
    ws[off + 0] = f2bf(vv[0]); ws[off + 1] = f2bf(vv[1]);
    ws[off + 2] = f2bf(vv[2]); ws[off + 3] = f2bf(vv[3]);
}

// 1024 blocks = 512 l-quads x 2 groups. Block: 64 rows (16 b x 4 l, row = li*16 + b),
// 320 cols (one g). 8 waves = 4 rg (16 rows) x 2 cg (160 cols); wave acc = 10 f32x4.
// launch_bounds (512,4): 128 regs/thread -> no accumulator spill (r4 lesson: (512,8)
// forced 64 regs and spilled acc to scratch -> 873 MB WRITE_SIZE).
template<bool HAS_WS>
__global__ __launch_bounds__(512, 4) void gvq5_kernel(
    const float* __restrict__ hidden,
    const float* __restrict__ W,
    const float* __restrict__ bias,
    const float* __restrict__ cb,
    const float* __restrict__ gn,
    float* __restrict__ out,
    const unsigned short* __restrict__ ws)
{
    __shared__ unsigned short Abuf[2][2][2048];          // [dbuf][hi/lo][4 chunks x 1 KB]
    __shared__ unsigned short Wb[HAS_WS ? 64 : 10240];   // fallback W-hi frag staging
    __shared__ float pm1[2][64], pm2[2][64], plx[2][64], psum[2][64];
    __shared__ int   pi1[2][64], pi2[2][64], IDX[64];

    const int tid  = threadIdx.x;
    const int w    = tid >> 6, lane = tid & 63;
    const int rg   = w >> 1, cg = w & 1;
    const int q    = lane >> 4, c = lane & 15;

    // XCD pairing: blocks d and d+8 (g=0/1 of same l-quad) -> same XCD
    const int d  = blockIdx.x;
    const int g  = (d >> 3) & 1;
    const int lq = (d >> 4) * 8 + (d & 7);
    const size_t lbase = (size_t)lq * 4;

    // ---- A staging map: 256 tasks x 2 planes; task -> (row r_, k-quarter kq) ----
    const int task = tid & 255, plane = tid >> 8;
    const int r_ = task >> 2, kq = task & 3;
    const int ab = r_ & 15, ali = r_ >> 4;               // b, l-in-quad
    const float* aptr = hidden + ((size_t)ab * L_ + (lbase + ali)) * D1_ + kq * 8;
    const int awoff = ali * 1024 + (((ab + kq * 16) << 4) ^ (kq << 4));
    const int rdoff = (lane << 4) ^ (lane & 48);         // swizzled frag-read byte offset

    f32x4 acc[10];
#pragma unroll
    for (int cf = 0; cf < 10; ++cf) acc[cf] = (f32x4){0.f, 0.f, 0.f, 0.f};

    const unsigned short* wsb = ws + ((size_t)(g * 20 + cg * 10) << 13) + (lane << 3);

    // ---- prologue: stage A(0) (+W(0) fallback) ----
    {
        float4 v0 = *(const float4*)(aptr);
        float4 v1 = *(const float4*)(aptr + 4);
        u16x8 hv, lv; cvt8(v0, v1, hv, lv);
        if (plane == 0) *(u16x8*)((char*)Abuf[0][0] + awoff) = hv;
        else            *(u16x8*)((char*)Abuf[0][1] + awoff) = lv;
        if (!HAS_WS) {
#pragma unroll
            for (int i = 0; i < 3; ++i) {
                int ti = tid + i * 512;
                if (ti < 1280) {
                    int oc = ti >> 2, kq2 = ti & 3;
                    const float* wp = W + ((size_t)(g * V_ + oc)) * D1_ + kq2 * 8;
                    float4 w0 = *(const float4*)(wp), w1 = *(const float4*)(wp + 4);
                    u16x8 h, l; cvt8(w0, w1, h, l);
                    int off = (oc >> 4) * 1024 + (((((oc & 15) + kq2 * 16) << 4)) ^ (kq2 << 4));
                    *(u16x8*)((char*)Wb + off) = h;
                }
            }
        }
    }

    int cur = 0;
#pragma unroll 1
    for (int kk = 0; kk < 16; ++kk) {
        float4 av0, av1, w00[3], w01[3];
        if (kk < 15) {
            av0 = *(const float4*)(aptr + (kk + 1) * 32);
            av1 = *(const float4*)(aptr + (kk + 1) * 32 + 4);
            if (!HAS_WS) {
#pragma unroll
                for (int i = 0; i < 3; ++i) {
                    int ti = tid + i * 512;
                    if (ti < 1280) {
                        int oc = ti >> 2, kq2 = ti & 3;
                        const float* wp = W + ((size_t)(g * V_ + oc)) * D1_ + (kk + 1) * 32 + kq2 * 8;
                        w00[i] = *(const float4*)(wp); w01[i] = *(const float4*)(wp + 4);
                    }
                }
            }
        }
        __syncthreads();

        const char* abh = (const char*)Abuf[cur][0] + rg * 1024 + rdoff;
        const char* abl = (const char*)Abuf[cur][1] + rg * 1024 + rdoff;
        s16x8 ah = *(const s16x8*)abh;
        s16x8 al = *(const s16x8*)abl;
#pragma unroll
        for (int cf = 0; cf < 10; ++cf) {
            s16x8 bh;
            if (HAS_WS) bh = *(const s16x8*)(wsb + cf * 8192 + kk * 512);
            else        bh = *(const s16x8*)((const char*)Wb + (cg * 10 + cf) * 1024 + rdoff);
            acc[cf] = __builtin_amdgcn_mfma_f32_16x16x32_bf16(ah, bh, acc[cf], 0, 0, 0);
            acc[cf] = __builtin_amdgcn_mfma_f32_16x16x32_bf16(al, bh, acc[cf], 0, 0, 0);
        }
        if (!HAS_WS) __syncthreads();
        if (kk < 15) {
            u16x8 hv, lv; cvt8(av0, av1, hv, lv);
            if (plane == 0) *(u16x8*)((char*)Abuf[cur ^ 1][0] + awoff) = hv;
            else            *(u16x8*)((char*)Abuf[cur ^ 1][1] + awoff) = lv;
            if (!HAS_WS) {
#pragma unroll
                for (int i = 0; i < 3; ++i) {
                    int ti = tid + i * 512;
                    if (ti < 1280) {
                        int oc = ti >> 2, kq2 = ti & 3;
                        u16x8 h, l; cvt8(w00[i], w01[i], h, l);
                        int off = (oc >> 4) * 1024 + (((((oc & 15) + kq2 * 16) << 4)) ^ (kq2 << 4));
                        *(u16x8*)((char*)Wb + off) = h;
                    }
                }
            }
            cur ^= 1;
        }
    }

    // ---- E1: bias ----
    const int lcol0 = cg * 160 + c;
    float bv[10];
#pragma unroll
    for (int cf = 0; cf < 10; ++cf) bv[cf] = bias[g * V_ + lcol0 + cf * 16];
#pragma unroll
    for (int cf = 0; cf < 10; ++cf)
#pragma unroll
        for (int r = 0; r < 4; ++r) acc[cf][r] += bv[cf];

    // ---- E2: per-row top2(logit+gumbel) + max(logit), per cg ----
    {
        const size_t lg2 = lbase + rg;
        size_t gbase[4];
#pragma unroll
        for (int r = 0; r < 4; ++r)
            gbase[r] = (((size_t)(q * 4 + r) * L_ + lg2) * G_ + g) * V_ + lcol0;
        float m1[4], m2[4], lx[4]; int i1[4], i2[4];
#pragma unroll
        for (int r = 0; r < 4; ++r) { m1[r] = -3e38f; m2[r] = -3e38f; lx[r] = -3e38f; i1[r] = 0; i2[r] = 0; }
#pragma unroll
        for (int cf = 0; cf < 10; ++cf) {
            const int col = lcol0 + cf * 16;
#pragma unroll
            for (int r = 0; r < 4; ++r) {
                float lg = acc[cf][r];
                float s  = lg + gn[gbase[r] + cf * 16];
                lx[r] = fmaxf(lx[r], lg);
                if (s > m1[r])      { m2[r] = m1[r]; i2[r] = i1[r]; m1[r] = s; i1[r] = col; }
                else if (s > m2[r]) { m2[r] = s; i2[r] = col; }
            }
        }
#pragma unroll
        for (int mk = 1; mk <= 8; mk <<= 1) {
#pragma unroll
            for (int r = 0; r < 4; ++r) {
                float om1 = __shfl_xor(m1[r], mk); int oi1 = __shfl_xor(i1[r], mk);
                float om2 = __shfl_xor(m2[r], mk); int oi2 = __shfl_xor(i2[r], mk);
                lx[r] = fmaxf(lx[r], __shfl_xor(lx[r], mk));
                merge2(m1[r], i1[r], m2[r], i2[r], om1, oi1, om2, oi2);
            }
        }
        if (c == 0) {
            int row0 = rg * 16 + q * 4;
            *(f32x4*)&pm1[cg][row0] = (f32x4){m1[0], m1[1], m1[2], m1[3]};
            *(s32x4*)&pi1[cg][row0] = (s32x4){i1[0], i1[1], i1[2], i1[3]};
            *(f32x4*)&pm2[cg][row0] = (f32x4){m2[0], m2[1], m2[2], m2[3]};
            *(s32x4*)&pi2[cg][row0] = (s32x4){i2[0], i2[1], i2[2], i2[3]};
            *(f32x4*)&plx[cg][row0] = (f32x4){lx[0], lx[1], lx[2], lx[3]};
        }
    }
    __syncthreads();

    // ---- E3a: row max -> exp -> row sum ----
    {
        int row0 = rg * 16 + q * 4;
        float LM[4], se[4];
#pragma unroll
        for (int r = 0; r < 4; ++r) { LM[r] = fmaxf(plx[0][row0 + r], plx[1][row0 + r]); se[r] = 0.f; }
#pragma unroll
        for (int cf = 0; cf < 10; ++cf)
#pragma unroll
            for (int r = 0; r < 4; ++r) {
                float e = __expf(acc[cf][r] - LM[r]);
                acc[cf][r] = e; se[r] += e;
            }
#pragma unroll
        for (int mk = 1; mk <= 8; mk <<= 1)
#pragma unroll
            for (int r = 0; r < 4; ++r) se[r] += __shfl_xor(se[r], mk);
        if (c == 0) *(f32x4*)&psum[cg][row0] = (f32x4){se[0], se[1], se[2], se[3]};
    }
    __syncthreads();

    // ---- E3b: scale, b-sum (r + q-shuffles), direct nt perp store ----
    {
        int row0 = rg * 16 + q * 4;
        float IZ[4];
#pragma unroll
        for (int r = 0; r < 4; ++r) IZ[r] = 1.0f / ((psum[0][row0 + r] + psum[1][row0 + r]) * 16.0f);
        size_t obase = OUT0_ + (lbase + rg) * GV_ + g * V_ + lcol0;
#pragma unroll
        for (int cf = 0; cf < 10; ++cf) {
            float pp = acc[cf][0] * IZ[0] + acc[cf][1] * IZ[1]
                     + acc[cf][2] * IZ[2] + acc[cf][3] * IZ[3];
            pp += __shfl_xor(pp, 16); pp += __shfl_xor(pp, 32);
            if (q == 0) __builtin_nontemporal_store(pp, &out[obase + cf * 16]);
        }
    }

    // ---- E6: argmax finalize + rare fp64 refine ----
    if (tid < 64) {
        const int row = tid;
        float M1 = pm1[0][row]; int I1 = pi1[0][row];
        float M2 = pm2[0][row]; int I2 = pi2[0][row];
        merge2(M1, I1, M2, I2, pm1[1][row], pi1[1][row], pm2[1][row], pi2[1][row]);
        int idx = I1;
        if (M1 - M2 < THR_) {
            const int b = row & 15, li = row >> 4;
            const size_t lg2 = lbase + li;
            const float* ar = hidden + ((size_t)b * L_ + lg2) * D1_;
            const int o1 = g * V_ + I1, o2 = g * V_ + I2;
            double s1 = (double)bias[o1], s2 = (double)bias[o2];
            const float* w1 = W + (size_t)o1 * D1_;
            const float* w2 = W + (size_t)o2 * D1_;
#pragma unroll 4
            for (int k = 0; k < D1_; ++k) {
                double a = (double)ar[k];
                s1 = fma(a, (double)w1[k], s1);
                s2 = fma(a, (double)w2[k], s2);
            }
            const size_t gb = (((size_t)b * L_ + lg2) * G_ + g) * V_;
            s1 += (double)gn[gb + I1]; s2 += (double)gn[gb + I2];
            if (s2 > s1 || (s2 == s1 && I2 < I1)) idx = I2;
        }
        IDX[row] = idx;
    }
    __syncthreads();

    // ---- E7: code-vector gather, nt stores ----
#pragma unroll 1
    for (int it = 0; it < 12; ++it) {
        int i = tid + it * 512;                 // 0..6143 float4-tasks (64 rows x 96)
        int row = i / 96, f = i - row * 96;
        int v = IDX[row];
        int b = row & 15, li = row >> 4;
        f32x4 val = *(const f32x4*)(cb + ((size_t)(g * V_ + v) * DG_) + f * 4);
        __builtin_nontemporal_store(val,
            (f32x4*)(out + ((size_t)b * L_ + lbase + li) * (G_ * DG_) + g * DG_ + f * 4));
    }
}

extern "C" void kernel_launch(void* const* d_in, const int* in_sizes, int n_in,
                              void* d_out, int out_size, void* d_ws, size_t ws_size,
                              hipStream_t stream) {
    const float* hidden   = (const float*)d_in[0];
    const float* W        = (const float*)d_in[1];
    const float* bias     = (const float*)d_in[2];
    const float* codebook = (const float*)d_in[3];
    const float* gumbel   = (const float*)d_in[4];
    float* out = (float*)d_out;

    if (ws_size >= WS_BYTES_) {
        prep_w_kernel<<<320, 256, 0, stream>>>(W, (unsigned short*)d_ws);
        gvq5_kernel<true><<<1024, 512, 0, stream>>>(hidden, W, bias, codebook, gumbel, out,
                                                    (const unsigned short*)d_ws);
    } else {
        gvq5_kernel<false><<<1024, 512, 0, stream>>>(hidden, W, bias, codebook, gumbel, out,
                                                     (const unsigned short*)d_ws);
    }
}